// Round 1
// baseline (44.229 us; speedup 1.0000x reference)
//
#include <hip/hip_runtime.h>

// NODE ensemble fused forward:
//   logits[b, t*6+d] = sum_i x[b,i] * fsel[t,d,i]  (bf16 MFMA, fp32 accum)
//   p = sigmoid(logits - thr); out[b] = sum_t fold(p, leaf_weights[t])
//
// B=16384, D=512, T=64, DEPTH=6, N=T*DEPTH=384, leaves=64.
// Grid: B/64 blocks x 256 threads (4 waves). Wave = 16 rows x all 384 cols.

#define DD      512
#define TT      64
#define NDEPTH  6
#define NCOL    384          // TT * NDEPTH
#define BM      64           // rows per block (4 waves x 16)
#define BK      64           // K chunk
#define FSROW   72           // padded bf16 row stride for fs chunk (+8 pad)
#define LPB     396          // padded bf16 row stride for logits

typedef __bf16 bf16_t;
typedef __bf16 bf16x8 __attribute__((ext_vector_type(8)));
typedef __bf16 bf16x4 __attribute__((ext_vector_type(4)));
typedef float  f32x4  __attribute__((ext_vector_type(4)));

__global__ __launch_bounds__(256) void node_fused_kernel(
    const float* __restrict__ x,      // [B][512]
    const float* __restrict__ fsel,   // [64][6][512] -> [384][512]
    const float* __restrict__ thr,    // [384]
    const float* __restrict__ lw,     // [64][64]
    float* __restrict__ out)          // [B]
{
  extern __shared__ char smem[];
  bf16_t* fsb = (bf16_t*)smem;        // [NCOL][FSROW] = 55296 B
  bf16_t* lgs = (bf16_t*)smem;        // logits reuse: [4 waves][16][LPB] = 50688 B

  const int tid  = threadIdx.x;
  const int lane = tid & 63;
  const int wv   = tid >> 6;
  const int rowbase = blockIdx.x * BM + wv * 16;

  const int c  = lane & 15;           // MFMA row (A) / col (B,D)
  const int kg = lane >> 4;           // k-group

  f32x4 acc[24];
  #pragma unroll
  for (int n = 0; n < 24; ++n) acc[n] = (f32x4){0.f, 0.f, 0.f, 0.f};

  const float* xr = x + (size_t)(rowbase + c) * DD + kg * 8;

  for (int kc = 0; kc < DD / BK; ++kc) {
    if (kc) __syncthreads();          // prior chunk's LDS reads done

    // ---- stage fs chunk (384 x 64) fp32 -> bf16 into LDS ----
    #pragma unroll 8
    for (int i = 0; i < 24; ++i) {
      int idx = i * 256 + tid;        // float4 index within chunk
      int e   = idx << 2;             // element index (0..24575)
      int n   = e >> 6;               // fs row (0..383)
      int k   = e & 63;               // col within chunk
      const float4 f = *reinterpret_cast<const float4*>(fsel + (size_t)n * DD + kc * BK + k);
      bf16x4 bv;
      bv[0] = (bf16_t)f.x; bv[1] = (bf16_t)f.y;
      bv[2] = (bf16_t)f.z; bv[3] = (bf16_t)f.w;
      *reinterpret_cast<bf16x4*>(fsb + n * FSROW + k) = bv;
    }
    __syncthreads();

    // ---- A fragments from global x (fp32 -> bf16) ----
    bf16x8 a[2];
    #pragma unroll
    for (int s = 0; s < 2; ++s) {
      float4 lo = *reinterpret_cast<const float4*>(xr + kc * BK + s * 32);
      float4 hi = *reinterpret_cast<const float4*>(xr + kc * BK + s * 32 + 4);
      bf16x8 av;
      av[0] = (bf16_t)lo.x; av[1] = (bf16_t)lo.y; av[2] = (bf16_t)lo.z; av[3] = (bf16_t)lo.w;
      av[4] = (bf16_t)hi.x; av[5] = (bf16_t)hi.y; av[6] = (bf16_t)hi.z; av[7] = (bf16_t)hi.w;
      a[s] = av;
    }

    // ---- MFMA: 24 col-frags x 2 k-steps ----
    const bf16_t* bb = fsb + c * FSROW + kg * 8;
    #pragma unroll
    for (int n = 0; n < 24; ++n) {
      bf16x8 b0 = *reinterpret_cast<const bf16x8*>(bb + n * 16 * FSROW);
      bf16x8 b1 = *reinterpret_cast<const bf16x8*>(bb + n * 16 * FSROW + 32);
      acc[n] = __builtin_amdgcn_mfma_f32_16x16x32_bf16(a[0], b0, acc[n], 0, 0, 0);
      acc[n] = __builtin_amdgcn_mfma_f32_16x16x32_bf16(a[1], b1, acc[n], 0, 0, 0);
    }
  }

  __syncthreads();  // all fs reads done before logits overwrite LDS

  // ---- spill logits to LDS (bf16), per-wave region ----
  // D layout: lane holds D[kg*4 + r][c] in acc[n][r], col = n*16 + c
  bf16_t* lg = lgs + wv * 16 * LPB;
  #pragma unroll
  for (int n = 0; n < 24; ++n) {
    #pragma unroll
    for (int r = 0; r < 4; ++r) {
      lg[(kg * 4 + r) * LPB + n * 16 + c] = (bf16_t)acc[n][r];
    }
  }
  __syncthreads();

  // ---- epilogue: lane = tree; fold leaf weights with sigmoids ----
  float w[64];
  #pragma unroll
  for (int j = 0; j < 16; ++j) {
    float4 f = *reinterpret_cast<const float4*>(lw + lane * 64 + j * 4);
    w[4*j] = f.x; w[4*j+1] = f.y; w[4*j+2] = f.z; w[4*j+3] = f.w;
  }
  float th[NDEPTH];
  #pragma unroll
  for (int d = 0; d < NDEPTH; ++d) th[d] = thr[lane * NDEPTH + d];

  for (int r = 0; r < 16; ++r) {
    const bf16_t* lrow = lg + r * LPB + lane * NDEPTH;
    float p[NDEPTH];
    #pragma unroll
    for (int d = 0; d < NDEPTH; ++d) {
      float z = (float)lrow[d] - th[d];
      p[d] = 1.0f / (1.0f + __expf(-z));
    }
    // bottom-up fold: leaf index bit (5-d) selects p[d] (bit=0) vs 1-p[d]
    float v[32];
    #pragma unroll
    for (int j = 0; j < 32; ++j) v[j] = fmaf(p[5], w[2*j] - w[2*j+1], w[2*j+1]);
    #pragma unroll
    for (int j = 0; j < 16; ++j) v[j] = fmaf(p[4], v[2*j] - v[2*j+1], v[2*j+1]);
    #pragma unroll
    for (int j = 0; j < 8;  ++j) v[j] = fmaf(p[3], v[2*j] - v[2*j+1], v[2*j+1]);
    #pragma unroll
    for (int j = 0; j < 4;  ++j) v[j] = fmaf(p[2], v[2*j] - v[2*j+1], v[2*j+1]);
    #pragma unroll
    for (int j = 0; j < 2;  ++j) v[j] = fmaf(p[1], v[2*j] - v[2*j+1], v[2*j+1]);
    float tv = fmaf(p[0], v[0] - v[1], v[1]);

    // sum over trees (64 lanes)
    #pragma unroll
    for (int off = 32; off; off >>= 1) tv += __shfl_xor(tv, off, 64);
    if (lane == 0) out[rowbase + r] = tv;
  }
}

extern "C" void kernel_launch(void* const* d_in, const int* in_sizes, int n_in,
                              void* d_out, int out_size, void* d_ws, size_t ws_size,
                              hipStream_t stream) {
  const float* x    = (const float*)d_in[0];
  const float* fsel = (const float*)d_in[1];
  const float* thr  = (const float*)d_in[2];
  const float* lw   = (const float*)d_in[3];
  float* out = (float*)d_out;

  const int B = in_sizes[0] / DD;          // 16384
  const int fs_lds   = NCOL * FSROW * 2;   // 55296 B
  const int lg_lds   = 4 * 16 * LPB * 2;   // 50688 B
  const int lds_size = fs_lds > lg_lds ? fs_lds : lg_lds;

  dim3 grid(B / BM), block(256);
  node_fused_kernel<<<grid, block, lds_size, stream>>>(x, fsel, thr, lw, out);
}